// Round 10
// baseline (365.185 us; speedup 1.0000x reference)
//
#include <hip/hip_runtime.h>

typedef unsigned short u16;
typedef unsigned int   u32;
typedef unsigned long long u64;
typedef _Float16 f16;
typedef f16 f16x8 __attribute__((ext_vector_type(8)));
typedef f16 f16x4 __attribute__((ext_vector_type(4)));
typedef float f32x4 __attribute__((ext_vector_type(4)));

#define N_ROWS 50000
#define D_DIM  2048
#define H_DIM  512
#define KSEL   5000

// ---------- workspace layout (bytes), ~7.3 MB ----------
#define W1F_OFF    0u          // 512*2048 f16 (2 MB)
#define SCORES_OFF 2097152u    // 50000 f32
#define HIST_OFF   2299152u    // 65536 u32 (256 KB)
#define S_OFF      2561296u    // 65536 u32
#define META_OFF   2823440u    // [0]=T, [1]=CTOT
#define KEYS_OFF   2823504u    // 50176 u64
#define SIDX_OFF   3224912u    // 5000 u32
#define SVAL_OFF   3244912u    // 5000 f32
#define AKW_OFF    3264912u    // 5000 f32
#define GPART_OFF  3285008u    // 512*2048 f32 (4 MB)

__device__ __forceinline__ u32 mono_bits(float s){
  u32 u = __float_as_uint(s);
  return (u & 0x80000000u) ? ~u : (u | 0x80000000u);
}
__device__ __forceinline__ float inv_mono(u32 u){
  u32 b = (u & 0x80000000u) ? (u & 0x7FFFFFFFu) : ~u;
  return __uint_as_float(b);
}
__device__ __forceinline__ void gload_lds16(const void* g, void* l){
  __builtin_amdgcn_global_load_lds((__attribute__((address_space(1))) void*)(void*)g,
                                   (__attribute__((address_space(3))) void*)l, 16, 0, 0);
}

// ---------- W1 -> fp16, fused hist clear ----------
// blocks 0..1023: convert W1 (1024*256*4 = 1048576 elems exact)
// blocks 1024..1087: clear hist (64*256 uint4 = 65536 u32)
__global__ void prep_w1_f16(const float* __restrict__ w1, f16* __restrict__ w1f,
                            u32* __restrict__ hist){
  if (blockIdx.x < 1024){
    int i = (blockIdx.x * 256 + threadIdx.x) * 4;
    float4 v = *(const float4*)(w1 + i);
    f16x4 h;
    h[0] = (f16)v.x; h[1] = (f16)v.y; h[2] = (f16)v.z; h[3] = (f16)v.w;
    *(f16x4*)(w1f + i) = h;
  } else {
    int i = (blockIdx.x - 1024) * 256 + threadIdx.x;
    ((uint4*)hist)[i] = make_uint4(0u, 0u, 0u, 0u);
  }
}

// ---------- fused scores GEMM: full-H, BK=64, single-buffer, no-asm ----------
// [UNCHANGED from R9 — measured best: 258 us, MfmaUtil 17%, FETCH 227 MB]
// Block 64 rows x ALL 512 h-cols, BK=64, 512 threads = 8 waves (1M x 8N),
// wave-tile 64x64. LDS: A 8 KB + B 64 KB + EPI 2 KB = 74 KB -> 2 blocks/CU.
// x read once globally (f32 reg-load + cvt + swizzled ds_write); W1 f16 via
// global_load_lds (L2-resident, pre-swizzled source). Plain __syncthreads.
// Epilogue: full score in-block -> scores[] + hist atomic.
__global__ __launch_bounds__(512, 4) void gemm_sb(
    const float* __restrict__ x, const f16* __restrict__ w1f,
    const float* __restrict__ b1, const float* __restrict__ w2,
    float* __restrict__ scores, u32* __restrict__ hist)
{
  __shared__ __align__(16) f16 Al[4096];     // 64 rows x 64 k (8 KB)
  __shared__ __align__(16) f16 Bl[32768];    // 512 rows x 64 k (64 KB)
  __shared__ float EPI[64][8];

  const int t = threadIdx.x, l = t & 63, w = t >> 6;   // w = col-block 0..7
  const int r0 = blockIdx.x * 64;

  f32x4 acc[4][4] = {};

  const int arow = t >> 3;
  int gr = r0 + arow; if (gr > N_ROWS - 1) gr = N_ROWS - 1;
  const float* asrc = x + (size_t)gr * D_DIM + (t & 7) * 8;
  const int adst = arow * 64 + (((t & 7) ^ (arow & 7)) << 3);    // f16 idx, XOR-swizzled

  const f16* bsrc = w1f + (size_t)(t >> 3) * D_DIM + (((t & 7) ^ ((t >> 3) & 7)) * 8);
  const int bdst = t * 8;                                        // + p*4096

  for (int kt = 0; kt < 32; ++kt){
    const int k0 = kt * 64;
    #pragma unroll
    for (int p = 0; p < 8; ++p)
      gload_lds16(bsrc + (size_t)p * 64 * D_DIM + k0, &Bl[p * 4096 + bdst]);
    {
      float4 v0 = *(const float4*)(asrc + k0);
      float4 v1 = *(const float4*)(asrc + k0 + 4);
      f16x8 h;
      h[0]=(f16)v0.x; h[1]=(f16)v0.y; h[2]=(f16)v0.z; h[3]=(f16)v0.w;
      h[4]=(f16)v1.x; h[5]=(f16)v1.y; h[6]=(f16)v1.z; h[7]=(f16)v1.w;
      *(f16x8*)&Al[adst] = h;
    }
    __syncthreads();

    __builtin_amdgcn_s_setprio(1);
    #pragma unroll
    for (int ks = 0; ks < 2; ++ks){
      const int chunk = ks * 4 + (l >> 4);
      f16x8 bfr[4];
      #pragma unroll
      for (int nt = 0; nt < 4; ++nt){
        int row = w * 64 + nt * 16 + (l & 15);
        bfr[nt] = *(const f16x8*)&Bl[row * 64 + ((chunk ^ (row & 7)) << 3)];
      }
      #pragma unroll
      for (int mt = 0; mt < 4; ++mt){
        int row = mt * 16 + (l & 15);
        f16x8 af = *(const f16x8*)&Al[row * 64 + ((chunk ^ (row & 7)) << 3)];
        #pragma unroll
        for (int nt = 0; nt < 4; ++nt)
          acc[mt][nt] = __builtin_amdgcn_mfma_f32_16x16x32_f16(af, bfr[nt], acc[mt][nt], 0, 0, 0);
      }
    }
    __builtin_amdgcn_s_setprio(0);
    __syncthreads();
  }

  #pragma unroll
  for (int mt = 0; mt < 4; ++mt){
    float rsum[4] = {0.f, 0.f, 0.f, 0.f};
    #pragma unroll
    for (int nt = 0; nt < 4; ++nt){
      int h = w * 64 + nt * 16 + (l & 15);
      float w2v = w2[h], b1v = b1[h];
      #pragma unroll
      for (int j = 0; j < 4; ++j)
        rsum[j] += tanhf(acc[mt][nt][j] + b1v) * w2v;
    }
    #pragma unroll
    for (int off = 1; off < 16; off <<= 1)
      #pragma unroll
      for (int j = 0; j < 4; ++j) rsum[j] += __shfl_xor(rsum[j], off, 64);
    if ((l & 15) == 0){
      int g = l >> 4;
      #pragma unroll
      for (int j = 0; j < 4; ++j) EPI[mt * 16 + g * 4 + j][w] = rsum[j];
    }
  }
  __syncthreads();
  if (t < 64){
    int n = r0 + t;
    if (n < N_ROWS){
      float s = 0.f;
      #pragma unroll
      for (int q = 0; q < 8; ++q) s += EPI[t][q];
      scores[n] = s;                                   // b2 omitted: cancels
      atomicAdd(&hist[mono_bits(s) >> 16], 1u);
    }
  }
}

// ---------- suffix scan: S[b] = #elems in bins > b; find threshold bin T ----------
__global__ __launch_bounds__(1024) void scan_S(const u32* __restrict__ hist,
                                               u32* __restrict__ S, u32* __restrict__ meta){
  __shared__ u32 csum[1024];
  const int t = threadIdx.x;
  u32 sum = 0;
  #pragma unroll 4
  for (int i = 0; i < 64; ++i) sum += hist[t * 64 + i];
  csum[t] = sum;
  __syncthreads();
  for (int off = 1; off < 1024; off <<= 1){
    u32 v = (t + off < 1024) ? csum[t + off] : 0u;
    __syncthreads();
    csum[t] += v;
    __syncthreads();
  }
  u32 running = (t < 1023) ? csum[t + 1] : 0u;    // elems in bins >= (t+1)*64
  for (int i = 63; i >= 0; --i){
    int b = t * 64 + i;
    u32 h = hist[b];
    S[b] = running;                                // count of bins > b
    if (running < (u32)KSEL && running + h >= (u32)KSEL){
      meta[0] = (u32)b;                            // threshold bin
      meta[1] = running + h;                       // CTOT
    }
    running += h;
  }
}

// ---------- scatter candidates to their bin segment ----------
__global__ void scatter_cand(const float* __restrict__ scores, u32* __restrict__ hist,
                             const u32* __restrict__ S, const u32* __restrict__ meta,
                             u64* __restrict__ keys){
  int n = blockIdx.x * 256 + threadIdx.x;
  if (n >= N_ROWS) return;
  u32 u = mono_bits(scores[n]);
  u32 b = u >> 16;
  if (b >= meta[0]){
    u32 rank = atomicSub(&hist[b], 1u) - 1u;
    u32 pos = S[b] + rank;
    keys[pos] = ((u64)u << 32) | (u32)(~n);        // value desc, index asc
  }
}

// ---------- rank-fix within bin segments + emit exact sorted top-k ----------
__global__ void emit_topk(const u64* __restrict__ keys, const u32* __restrict__ S,
                          const u32* __restrict__ meta,
                          u32* __restrict__ sidx, float* __restrict__ svals){
  u32 p = blockIdx.x * 256 + threadIdx.x;
  u32 CTOT = meta[1];
  if (p >= CTOT) return;
  u64 key = keys[p];
  u32 b = (u32)(key >> 48);
  u32 lo = S[b];
  u32 hi = (b > 0) ? S[b - 1] : CTOT;
  u32 c = 0;
  for (u32 q = lo; q < hi; ++q) c += (keys[q] > key);
  u32 r = lo + c;
  if (r < (u32)KSEL){
    sidx[r] = ~(u32)(key & 0xFFFFFFFFull);
    svals[r] = inv_mono((u32)(key >> 32));
  }
}

// ---------- softmax over top-k (global Z and b2 cancel; renormalize) ----------
__global__ __launch_bounds__(1024) void softmax_topk(
    const float* __restrict__ svals, float* __restrict__ akw, float* __restrict__ out)
{
  __shared__ float red[1024];
  const int t = threadIdx.x;
  float m = svals[0];
  float ev[5];
  float local = 0.f;
  #pragma unroll
  for (int r = 0; r < 5; ++r){
    int j = t + r * 1024;
    if (j < KSEL){ ev[r] = expf(svals[j] - m); local += ev[r]; }
  }
  red[t] = local;
  __syncthreads();
  for (int o = 512; o > 0; o >>= 1){ if (t < o) red[t] += red[t + o]; __syncthreads(); }
  float Ssum = red[0];
  #pragma unroll
  for (int r = 0; r < 5; ++r){
    int j = t + r * 1024;
    if (j < KSEL){
      float a = ev[r] / Ssum;
      akw[j] = a; out[D_DIM + j] = a;
    }
  }
}

// ---------- gather + weighted sum (deterministic 2-pass, 512 blocks) ----------
__global__ void gather_M(const float* __restrict__ x, const u32* __restrict__ sidx,
                         const float* __restrict__ akw, float* __restrict__ gpart){
  int t = threadIdx.x, b = blockIdx.x;   // 512 blocks -> ~10 keys each
  float a8[8] = {0.f,0.f,0.f,0.f,0.f,0.f,0.f,0.f};
  for (int j = b; j < KSEL; j += 512){
    float a = akw[j];
    const float* xr = x + (size_t)sidx[j] * D_DIM;
    #pragma unroll
    for (int c = 0; c < 8; ++c) a8[c] += a * xr[t + c * 256];
  }
  #pragma unroll
  for (int c = 0; c < 8; ++c) gpart[(size_t)b * D_DIM + t + c * 256] = a8[c];
}
__global__ void reduce_M(const float* __restrict__ gpart, float* __restrict__ out){
  int d = blockIdx.x * 256 + threadIdx.x;
  float s = 0.f;
  for (int b = 0; b < 512; ++b) s += gpart[(size_t)b * D_DIM + d];
  out[d] = s;
}

extern "C" void kernel_launch(void* const* d_in, const int* in_sizes, int n_in,
                              void* d_out, int out_size, void* d_ws, size_t ws_size,
                              hipStream_t stream) {
  const float* x  = (const float*)d_in[0];
  const float* W1 = (const float*)d_in[1];
  const float* b1 = (const float*)d_in[2];
  const float* W2 = (const float*)d_in[3];
  // b2 (d_in[4]) cancels in softmax/top-k -> unused
  float* out = (float*)d_out;
  char* ws = (char*)d_ws;

  f16* w1f     = (f16*)(ws + W1F_OFF);
  float* scr   = (float*)(ws + SCORES_OFF);
  u32* hist    = (u32*)(ws + HIST_OFF);
  u32* Sarr    = (u32*)(ws + S_OFF);
  u32* meta    = (u32*)(ws + META_OFF);
  u64* keys    = (u64*)(ws + KEYS_OFF);
  u32* sidx    = (u32*)(ws + SIDX_OFF);
  float* svals = (float*)(ws + SVAL_OFF);
  float* akw   = (float*)(ws + AKW_OFF);
  float* gpart = (float*)(ws + GPART_OFF);

  (void)in_sizes; (void)n_in; (void)out_size; (void)ws_size;

  prep_w1_f16<<<1088, 256, 0, stream>>>(W1, w1f, hist);
  gemm_sb<<<782, 512, 0, stream>>>(x, w1f, b1, W2, scr, hist);
  scan_S<<<1, 1024, 0, stream>>>(hist, Sarr, meta);
  scatter_cand<<<196, 256, 0, stream>>>(scr, hist, Sarr, meta, keys);
  emit_topk<<<196, 256, 0, stream>>>(keys, Sarr, meta, sidx, svals);
  softmax_topk<<<1, 1024, 0, stream>>>(svals, akw, out);
  gather_M<<<512, 256, 0, stream>>>(x, sidx, akw, gpart);
  reduce_M<<<8, 256, 0, stream>>>(gpart, out);
}

// Round 11
// 339.823 us; speedup vs baseline: 1.0746x; 1.0746x over previous
//
#include <hip/hip_runtime.h>

typedef unsigned short u16;
typedef unsigned int   u32;
typedef unsigned long long u64;
typedef _Float16 f16;
typedef f16 f16x8 __attribute__((ext_vector_type(8)));
typedef f16 f16x4 __attribute__((ext_vector_type(4)));
typedef float f32x4 __attribute__((ext_vector_type(4)));

#define N_ROWS 50000
#define D_DIM  2048
#define H_DIM  512
#define KSEL   5000

// ---------- workspace layout (bytes), ~7.3 MB ----------
#define W1F_OFF    0u          // 512*2048 f16 (2 MB)
#define SCORES_OFF 2097152u    // 50000 f32
#define HIST_OFF   2299152u    // 65536 u32 (256 KB)
#define S_OFF      2561296u    // 65536 u32
#define META_OFF   2823440u    // [0]=T, [1]=CTOT
#define KEYS_OFF   2823504u    // 50176 u64
#define SIDX_OFF   3224912u    // 5000 u32
#define SVAL_OFF   3244912u    // 5000 f32
#define AKW_OFF    3264912u    // 5000 f32
#define GPART_OFF  3285008u    // 512*2048 f32 (4 MB)

__device__ __forceinline__ u32 mono_bits(float s){
  u32 u = __float_as_uint(s);
  return (u & 0x80000000u) ? ~u : (u | 0x80000000u);
}
__device__ __forceinline__ float inv_mono(u32 u){
  u32 b = (u & 0x80000000u) ? (u & 0x7FFFFFFFu) : ~u;
  return __uint_as_float(b);
}
__device__ __forceinline__ void gload_lds16(const void* g, void* l){
  __builtin_amdgcn_global_load_lds((__attribute__((address_space(1))) void*)(void*)g,
                                   (__attribute__((address_space(3))) void*)l, 16, 0, 0);
}

// ---------- W1 -> fp16, fused hist clear ----------
__global__ void prep_w1_f16(const float* __restrict__ w1, f16* __restrict__ w1f,
                            u32* __restrict__ hist){
  if (blockIdx.x < 1024){
    int i = (blockIdx.x * 256 + threadIdx.x) * 4;
    float4 v = *(const float4*)(w1 + i);
    f16x4 h;
    h[0] = (f16)v.x; h[1] = (f16)v.y; h[2] = (f16)v.z; h[3] = (f16)v.w;
    *(f16x4*)(w1f + i) = h;
  } else {
    int i = (blockIdx.x - 1024) * 256 + threadIdx.x;
    ((uint4*)hist)[i] = make_uint4(0u, 0u, 0u, 0u);
  }
}

// ---------- fused scores GEMM: full-H, BK=64, A-dbuf + x-reg-prefetch ----------
// R9 geometry (measured best) + two serial-latency fixes:
//  (1) x(t+1) global->reg load issued INSIDE tile t's compute region (before
//      MFMAs) -> ~900cy HBM latency hides under compute. Loads can't cross
//      s_barrier, so source placement pins the overlap.
//  (2) A double-buffered (+8 KB): cvt+ds_write of x(t+1) lands in Al[cur^1]
//      right after the post-compute barrier, off the serial window. B stays
//      single-buffered (L2 latency ~250cy is the only serial item left).
// LDS = A 2x8KB + B 64KB = exactly 80 KB -> 2 blocks/CU kept. EPI aliases Bl.
// No inline asm; 2 barriers/tile; compiler owns all waitcnts.
__global__ __launch_bounds__(512, 4) void gemm_pf(
    const float* __restrict__ x, const f16* __restrict__ w1f,
    const float* __restrict__ b1, const float* __restrict__ w2,
    float* __restrict__ scores, u32* __restrict__ hist)
{
  __shared__ __align__(16) f16 Al[2][4096];  // 64 rows x 64 k per buf (8 KB each)
  __shared__ __align__(16) f16 Bl[32768];    // 512 rows x 64 k (64 KB)

  const int t = threadIdx.x, l = t & 63, w = t >> 6;   // w = col-block 0..7
  const int r0 = blockIdx.x * 64;

  f32x4 acc[4][4] = {};

  // A staging: thread t -> row t>>3 (0..63), 8-f32 group t&7.
  const int arow = t >> 3;
  int gr = r0 + arow; if (gr > N_ROWS - 1) gr = N_ROWS - 1;
  const float* asrc = x + (size_t)gr * D_DIM + (t & 7) * 8;
  const int adst = arow * 64 + (((t & 7) ^ (arow & 7)) << 3);    // f16 idx, XOR-swizzled

  // B staging: pass p -> row p*64 + (t>>3), chunk slot t&7; source pre-swizzled,
  // LDS dest lane-linear.
  const f16* bsrc = w1f + (size_t)(t >> 3) * D_DIM + (((t & 7) ^ ((t >> 3) & 7)) * 8);
  const int bdst = t * 8;                                        // + p*4096

  // ---- prologue: stage tile 0 (B -> LDS, x(0) -> regs -> Al[0]) ----
  {
    #pragma unroll
    for (int p = 0; p < 8; ++p)
      gload_lds16(bsrc + (size_t)p * 64 * D_DIM, &Bl[p * 4096 + bdst]);
    float4 v0 = *(const float4*)(asrc);
    float4 v1 = *(const float4*)(asrc + 4);
    f16x8 h;
    h[0]=(f16)v0.x; h[1]=(f16)v0.y; h[2]=(f16)v0.z; h[3]=(f16)v0.w;
    h[4]=(f16)v1.x; h[5]=(f16)v1.y; h[6]=(f16)v1.z; h[7]=(f16)v1.w;
    *(f16x8*)&Al[0][adst] = h;
  }
  __syncthreads();   // tile 0 visible

  for (int kt = 0; kt < 32; ++kt){
    const int cur = kt & 1;
    const f16* Ab = Al[cur];

    // (1) x(t+1) -> regs, issued before the MFMA cluster (latency hides here)
    float4 v0, v1;
    if (kt + 1 < 32){
      const int k0 = (kt + 1) * 64;
      v0 = *(const float4*)(asrc + k0);
      v1 = *(const float4*)(asrc + k0 + 4);
    }

    __builtin_amdgcn_s_setprio(1);
    #pragma unroll
    for (int ks = 0; ks < 2; ++ks){
      const int chunk = ks * 4 + (l >> 4);
      f16x8 bfr[4];
      #pragma unroll
      for (int nt = 0; nt < 4; ++nt){
        int row = w * 64 + nt * 16 + (l & 15);
        bfr[nt] = *(const f16x8*)&Bl[row * 64 + ((chunk ^ (row & 7)) << 3)];
      }
      #pragma unroll
      for (int mt = 0; mt < 4; ++mt){
        int row = mt * 16 + (l & 15);
        f16x8 af = *(const f16x8*)&Ab[row * 64 + ((chunk ^ (row & 7)) << 3)];
        #pragma unroll
        for (int nt = 0; nt < 4; ++nt)
          acc[mt][nt] = __builtin_amdgcn_mfma_f32_16x16x32_f16(af, bfr[nt], acc[mt][nt], 0, 0, 0);
      }
    }
    __builtin_amdgcn_s_setprio(0);
    __syncthreads();   // all waves done reading Bl + Al[cur]

    if (kt + 1 < 32){
      const int k0 = (kt + 1) * 64;
      // (2) B(t+1) staging first (longest latency), then A(t+1) write to Al[cur^1]
      #pragma unroll
      for (int p = 0; p < 8; ++p)
        gload_lds16(bsrc + (size_t)p * 64 * D_DIM + k0, &Bl[p * 4096 + bdst]);
      f16x8 h;
      h[0]=(f16)v0.x; h[1]=(f16)v0.y; h[2]=(f16)v0.z; h[3]=(f16)v0.w;
      h[4]=(f16)v1.x; h[5]=(f16)v1.y; h[6]=(f16)v1.z; h[7]=(f16)v1.w;
      *(f16x8*)&Al[cur ^ 1][adst] = h;
    }
    __syncthreads();   // next tile staged & visible
  }

  // ---- epilogue: full score in-block (EPI aliases Bl; compute is done) ----
  // acc[mt][nt] reg j: row = mt*16 + (l>>4)*4 + j, col = w*64 + nt*16 + (l&15)
  float (*EPI)[8] = (float(*)[8])Bl;
  #pragma unroll
  for (int mt = 0; mt < 4; ++mt){
    float rsum[4] = {0.f, 0.f, 0.f, 0.f};
    #pragma unroll
    for (int nt = 0; nt < 4; ++nt){
      int h = w * 64 + nt * 16 + (l & 15);
      float w2v = w2[h], b1v = b1[h];
      #pragma unroll
      for (int j = 0; j < 4; ++j)
        rsum[j] += tanhf(acc[mt][nt][j] + b1v) * w2v;
    }
    #pragma unroll
    for (int off = 1; off < 16; off <<= 1)
      #pragma unroll
      for (int j = 0; j < 4; ++j) rsum[j] += __shfl_xor(rsum[j], off, 64);
    if ((l & 15) == 0){
      int g = l >> 4;
      #pragma unroll
      for (int j = 0; j < 4; ++j) EPI[mt * 16 + g * 4 + j][w] = rsum[j];
    }
  }
  __syncthreads();
  if (t < 64){
    int n = r0 + t;
    if (n < N_ROWS){
      float s = 0.f;
      #pragma unroll
      for (int q = 0; q < 8; ++q) s += EPI[t][q];
      scores[n] = s;                                   // b2 omitted: cancels
      atomicAdd(&hist[mono_bits(s) >> 16], 1u);
    }
  }
}

// ---------- suffix scan: S[b] = #elems in bins > b; find threshold bin T ----------
__global__ __launch_bounds__(1024) void scan_S(const u32* __restrict__ hist,
                                               u32* __restrict__ S, u32* __restrict__ meta){
  __shared__ u32 csum[1024];
  const int t = threadIdx.x;
  u32 sum = 0;
  #pragma unroll 4
  for (int i = 0; i < 64; ++i) sum += hist[t * 64 + i];
  csum[t] = sum;
  __syncthreads();
  for (int off = 1; off < 1024; off <<= 1){
    u32 v = (t + off < 1024) ? csum[t + off] : 0u;
    __syncthreads();
    csum[t] += v;
    __syncthreads();
  }
  u32 running = (t < 1023) ? csum[t + 1] : 0u;    // elems in bins >= (t+1)*64
  for (int i = 63; i >= 0; --i){
    int b = t * 64 + i;
    u32 h = hist[b];
    S[b] = running;                                // count of bins > b
    if (running < (u32)KSEL && running + h >= (u32)KSEL){
      meta[0] = (u32)b;                            // threshold bin
      meta[1] = running + h;                       // CTOT
    }
    running += h;
  }
}

// ---------- scatter candidates to their bin segment ----------
__global__ void scatter_cand(const float* __restrict__ scores, u32* __restrict__ hist,
                             const u32* __restrict__ S, const u32* __restrict__ meta,
                             u64* __restrict__ keys){
  int n = blockIdx.x * 256 + threadIdx.x;
  if (n >= N_ROWS) return;
  u32 u = mono_bits(scores[n]);
  u32 b = u >> 16;
  if (b >= meta[0]){
    u32 rank = atomicSub(&hist[b], 1u) - 1u;
    u32 pos = S[b] + rank;
    keys[pos] = ((u64)u << 32) | (u32)(~n);        // value desc, index asc
  }
}

// ---------- rank-fix within bin segments + emit exact sorted top-k ----------
__global__ void emit_topk(const u64* __restrict__ keys, const u32* __restrict__ S,
                          const u32* __restrict__ meta,
                          u32* __restrict__ sidx, float* __restrict__ svals){
  u32 p = blockIdx.x * 256 + threadIdx.x;
  u32 CTOT = meta[1];
  if (p >= CTOT) return;
  u64 key = keys[p];
  u32 b = (u32)(key >> 48);
  u32 lo = S[b];
  u32 hi = (b > 0) ? S[b - 1] : CTOT;
  u32 c = 0;
  for (u32 q = lo; q < hi; ++q) c += (keys[q] > key);
  u32 r = lo + c;
  if (r < (u32)KSEL){
    sidx[r] = ~(u32)(key & 0xFFFFFFFFull);
    svals[r] = inv_mono((u32)(key >> 32));
  }
}

// ---------- softmax over top-k (global Z and b2 cancel; renormalize) ----------
__global__ __launch_bounds__(1024) void softmax_topk(
    const float* __restrict__ svals, float* __restrict__ akw, float* __restrict__ out)
{
  __shared__ float red[1024];
  const int t = threadIdx.x;
  float m = svals[0];
  float ev[5];
  float local = 0.f;
  #pragma unroll
  for (int r = 0; r < 5; ++r){
    int j = t + r * 1024;
    if (j < KSEL){ ev[r] = expf(svals[j] - m); local += ev[r]; }
  }
  red[t] = local;
  __syncthreads();
  for (int o = 512; o > 0; o >>= 1){ if (t < o) red[t] += red[t + o]; __syncthreads(); }
  float Ssum = red[0];
  #pragma unroll
  for (int r = 0; r < 5; ++r){
    int j = t + r * 1024;
    if (j < KSEL){
      float a = ev[r] / Ssum;
      akw[j] = a; out[D_DIM + j] = a;
    }
  }
}

// ---------- gather + weighted sum (deterministic 2-pass, 512 blocks) ----------
__global__ void gather_M(const float* __restrict__ x, const u32* __restrict__ sidx,
                         const float* __restrict__ akw, float* __restrict__ gpart){
  int t = threadIdx.x, b = blockIdx.x;   // 512 blocks -> ~10 keys each
  float a8[8] = {0.f,0.f,0.f,0.f,0.f,0.f,0.f,0.f};
  for (int j = b; j < KSEL; j += 512){
    float a = akw[j];
    const float* xr = x + (size_t)sidx[j] * D_DIM;
    #pragma unroll
    for (int c = 0; c < 8; ++c) a8[c] += a * xr[t + c * 256];
  }
  #pragma unroll
  for (int c = 0; c < 8; ++c) gpart[(size_t)b * D_DIM + t + c * 256] = a8[c];
}
__global__ void reduce_M(const float* __restrict__ gpart, float* __restrict__ out){
  int d = blockIdx.x * 256 + threadIdx.x;
  float s = 0.f;
  for (int b = 0; b < 512; ++b) s += gpart[(size_t)b * D_DIM + d];
  out[d] = s;
}

extern "C" void kernel_launch(void* const* d_in, const int* in_sizes, int n_in,
                              void* d_out, int out_size, void* d_ws, size_t ws_size,
                              hipStream_t stream) {
  const float* x  = (const float*)d_in[0];
  const float* W1 = (const float*)d_in[1];
  const float* b1 = (const float*)d_in[2];
  const float* W2 = (const float*)d_in[3];
  // b2 (d_in[4]) cancels in softmax/top-k -> unused
  float* out = (float*)d_out;
  char* ws = (char*)d_ws;

  f16* w1f     = (f16*)(ws + W1F_OFF);
  float* scr   = (float*)(ws + SCORES_OFF);
  u32* hist    = (u32*)(ws + HIST_OFF);
  u32* Sarr    = (u32*)(ws + S_OFF);
  u32* meta    = (u32*)(ws + META_OFF);
  u64* keys    = (u64*)(ws + KEYS_OFF);
  u32* sidx    = (u32*)(ws + SIDX_OFF);
  float* svals = (float*)(ws + SVAL_OFF);
  float* akw   = (float*)(ws + AKW_OFF);
  float* gpart = (float*)(ws + GPART_OFF);

  (void)in_sizes; (void)n_in; (void)out_size; (void)ws_size;

  prep_w1_f16<<<1088, 256, 0, stream>>>(W1, w1f, hist);
  gemm_pf<<<782, 512, 0, stream>>>(x, w1f, b1, W2, scr, hist);
  scan_S<<<1, 1024, 0, stream>>>(hist, Sarr, meta);
  scatter_cand<<<196, 256, 0, stream>>>(scr, hist, Sarr, meta, keys);
  emit_topk<<<196, 256, 0, stream>>>(keys, Sarr, meta, sidx, svals);
  softmax_topk<<<1, 1024, 0, stream>>>(svals, akw, out);
  gather_M<<<512, 256, 0, stream>>>(x, sidx, akw, gpart);
  reduce_M<<<8, 256, 0, stream>>>(gpart, out);
}